// Round 7
// baseline (788.655 us; speedup 1.0000x reference)
//
#include <hip/hip_runtime.h>

// ---------------------------------------------------------------------------
// Problem constants
// ---------------------------------------------------------------------------
#define N_PFAS 20000
#define N_GW   100000
#define N_SW   30000
#define E_PG   1600000
#define E_GP   640000
#define E_PS   480000
#define E_SP   320000
#define E_TOT  (E_PG + E_PS + E_GP + E_SP)
// Concatenated node-count layout: [pg: N_GW][ps: N_SW][gp: N_PFAS][sp: N_PFAS]
#define BASE_PG 0
#define BASE_PS (N_GW)
#define BASE_GP (N_GW + N_SW)
#define BASE_SP (N_GW + N_SW + N_PFAS)
#define NTOT    (N_GW + N_SW + 2 * N_PFAS)
#define SCAN_NBLK ((NTOT + 2047) / 2048)
// Bucketed permute: 256 nodes per bucket.
#define NB        ((NTOT + 255) / 256)       // 665
#define BIN_EPT   12                         // edges per thread in bin pass
#define BIN_EPB   (1024 * BIN_EPT)           // 12288 edges per block
#define BIN_NBLK  ((E_TOT + BIN_EPB - 1) / BIN_EPB)
#define SEG_CAP   15360                      // LDS perm-segment capacity

// ---------------------------------------------------------------------------
// bf16 helpers (RNE pack, cheap unpack)
// ---------------------------------------------------------------------------
__device__ __forceinline__ unsigned short f2bf(float f) {
    unsigned u = __float_as_uint(f);
    u += 0x7fffu + ((u >> 16) & 1u);
    return (unsigned short)(u >> 16);
}
__device__ __forceinline__ float u2f(unsigned u) { return __uint_as_float(u); }

// ---------------------------------------------------------------------------
// Shared 128x128 GEMM tile: NT threads, 128 rows/block, 32-k chunks in LDS.
// ---------------------------------------------------------------------------
template<int NT>
__device__ __forceinline__ void tile_gemm(
    const float* __restrict__ X, const float* __restrict__ Wa,
    const float* __restrict__ Wb, int n, int row0, int tid,
    float4* sW4, float* sX, float4* acc)
{
    constexpr int TY  = NT / 32;
    constexpr int RPT = 128 / TY;
    const int tx = tid & 31;
    const int ty = tid >> 5;
    const float4* X4 = (const float4*)X;
    const float4* Wa4 = (const float4*)Wa;
    const float4* Wb4 = (const float4*)Wb;

    for (int kc = 0; kc < 4; ++kc) {
        __syncthreads();
        for (int i = tid; i < 1024; i += NT) {
            float4 w = Wa4[kc * 1024 + i];
            if (Wb) {
                float4 b = Wb4[kc * 1024 + i];
                w.x += b.x; w.y += b.y; w.z += b.z; w.w += b.w;
            }
            sW4[i] = w;
        }
        for (int j = tid; j < 1024; j += NT) {
            int rr = j >> 3, k4 = j & 7;
            int r = row0 + rr;
            float4 xv = make_float4(0.f, 0.f, 0.f, 0.f);
            if (r < n) xv = X4[(size_t)r * 32 + kc * 8 + k4];
            int kk = k4 * 4;
            sX[(kk + 0) * 128 + rr] = xv.x;
            sX[(kk + 1) * 128 + rr] = xv.y;
            sX[(kk + 2) * 128 + rr] = xv.z;
            sX[(kk + 3) * 128 + rr] = xv.w;
        }
        __syncthreads();
#pragma unroll 4
        for (int k = 0; k < 32; ++k) {
            float4 w4 = sW4[k * 32 + tx];
            const float4* xr4 = (const float4*)&sX[k * 128 + ty * RPT];
#pragma unroll
            for (int q = 0; q < RPT / 4; ++q) {
                float4 x4 = xr4[q];
                acc[q * 4 + 0].x += x4.x * w4.x; acc[q * 4 + 0].y += x4.x * w4.y;
                acc[q * 4 + 0].z += x4.x * w4.z; acc[q * 4 + 0].w += x4.x * w4.w;
                acc[q * 4 + 1].x += x4.y * w4.x; acc[q * 4 + 1].y += x4.y * w4.y;
                acc[q * 4 + 1].z += x4.y * w4.z; acc[q * 4 + 1].w += x4.y * w4.w;
                acc[q * 4 + 2].x += x4.z * w4.x; acc[q * 4 + 2].y += x4.z * w4.y;
                acc[q * 4 + 2].z += x4.z * w4.z; acc[q * 4 + 2].w += x4.z * w4.w;
                acc[q * 4 + 3].x += x4.w * w4.x; acc[q * 4 + 3].y += x4.w * w4.y;
                acc[q * 4 + 3].z += x4.w * w4.z; acc[q * 4 + 3].w += x4.w * w4.w;
            }
        }
    }
}

// ---------------------------------------------------------------------------
// bufT16 = X @ W  (bf16 output). grid.y selects (W0,out0) vs (W1,out1).
// launch_bounds(256,2): <=256 VGPR — kernel needs ~110, NO SPILL (grid-limited
// anyway: 157 blocks << 256 CUs, occupancy cap irrelevant).
// ---------------------------------------------------------------------------
__global__ __launch_bounds__(256, 2) void gemm_t16_kernel(
    int n, const float* __restrict__ X,
    const float* __restrict__ W0, unsigned short* __restrict__ out0,
    const float* __restrict__ W1, unsigned short* __restrict__ out1)
{
    __shared__ float sW[32 * 128];
    __shared__ float sX[32 * 128];
    const int tid = threadIdx.x;
    const int row0 = blockIdx.x * 128;
    const float* W = (blockIdx.y == 0) ? W0 : W1;
    unsigned short* out = (blockIdx.y == 0) ? out0 : out1;

    float4 acc[16];
#pragma unroll
    for (int i = 0; i < 16; ++i) acc[i] = make_float4(0.f, 0.f, 0.f, 0.f);
    tile_gemm<256>(X, W, nullptr, n, row0, tid, (float4*)sW, sX, acc);

    const int tx = tid & 31;
    const int rbase = row0 + (tid >> 5) * 16;
#pragma unroll
    for (int rr = 0; rr < 16; ++rr) {
        int r = rbase + rr;
        if (r < n) {
            uint2 o;
            o.x = (unsigned)f2bf(acc[rr].x) | ((unsigned)f2bf(acc[rr].y) << 16);
            o.y = (unsigned)f2bf(acc[rr].z) | ((unsigned)f2bf(acc[rr].w) << 16);
            *(uint2*)(out + (size_t)r * 128 + tx * 4) = o;
        }
    }
}

// ---------------------------------------------------------------------------
// gw/sw node pass, 512 threads: GEMM X@Wr fused with CSR gather of bf16
// transformed neighbor rows + scalar head.
// launch_bounds(512,4): <=128 VGPR/wave, 2 blocks/CU. The previous (512,8)
// capped at 64 VGPR -> acc[] spilled to scratch (254 MB HBM write/dispatch!).
// ---------------------------------------------------------------------------
__global__ __launch_bounds__(512, 4) void gemm_gather_scalar_kernel(
    int n, const float* __restrict__ X, const float* __restrict__ Wr,
    const float* __restrict__ bl,
    const unsigned short* __restrict__ bufT16, const int* __restrict__ perm,
    const int* __restrict__ off,
    const float* __restrict__ wout, const float* __restrict__ bout,
    float* __restrict__ out)
{
    __shared__ float sW[32 * 128];
    __shared__ float sX[32 * 128];
    const int tid = threadIdx.x;
    const int row0 = blockIdx.x * 128;
    float4 acc[8];
#pragma unroll
    for (int i = 0; i < 8; ++i) acc[i] = make_float4(0.f, 0.f, 0.f, 0.f);
    tile_gemm<512>(X, Wr, nullptr, n, row0, tid, (float4*)sW, sX, acc);

    const int tx = tid & 31;
    const int rbase = row0 + (tid >> 5) * 8;
    float4 bv = ((const float4*)bl)[tx];
    float4 wo = ((const float4*)wout)[tx];
    float bo = bout[0];

#pragma unroll 1
    for (int rr = 0; rr < 8; ++rr) {
        int r = rbase + rr;
        int lo = 0, hi = 0;
        if (r < n) { lo = off[r]; hi = off[r + 1]; }
        float4 s0 = make_float4(0.f, 0.f, 0.f, 0.f);
        float4 s1 = make_float4(0.f, 0.f, 0.f, 0.f);
        int i = lo;
        for (; i + 2 <= hi; i += 2) {
            int a = perm[i];
            int b = perm[i + 1];
            uint2 va = *(const uint2*)(bufT16 + (size_t)a * 128 + tx * 4);
            uint2 vb = *(const uint2*)(bufT16 + (size_t)b * 128 + tx * 4);
            s0.x += u2f(va.x << 16); s0.y += u2f(va.x & 0xffff0000u);
            s0.z += u2f(va.y << 16); s0.w += u2f(va.y & 0xffff0000u);
            s1.x += u2f(vb.x << 16); s1.y += u2f(vb.x & 0xffff0000u);
            s1.z += u2f(vb.y << 16); s1.w += u2f(vb.y & 0xffff0000u);
        }
        if (i < hi) {
            int a = perm[i];
            uint2 va = *(const uint2*)(bufT16 + (size_t)a * 128 + tx * 4);
            s0.x += u2f(va.x << 16); s0.y += u2f(va.x & 0xffff0000u);
            s0.z += u2f(va.y << 16); s0.w += u2f(va.y & 0xffff0000u);
        }
        float inv = 1.0f / fmaxf((float)(hi - lo), 1.0f);
        float h0 = fmaxf(acc[rr].x + bv.x + (s0.x + s1.x) * inv, 0.f);
        float h1 = fmaxf(acc[rr].y + bv.y + (s0.y + s1.y) * inv, 0.f);
        float h2 = fmaxf(acc[rr].z + bv.z + (s0.z + s1.z) * inv, 0.f);
        float h3 = fmaxf(acc[rr].w + bv.w + (s0.w + s1.w) * inv, 0.f);
        float p = h0 * wo.x + h1 * wo.y + h2 * wo.z + h3 * wo.w;
        p += __shfl_xor(p, 1, 32);
        p += __shfl_xor(p, 2, 32);
        p += __shfl_xor(p, 4, 32);
        p += __shfl_xor(p, 8, 32);
        p += __shfl_xor(p, 16, 32);
        if (tx == 0 && r < n) out[r] = p + bo;
    }
}

// ---------------------------------------------------------------------------
// pfas node pass: h_pf = relu(mean_g@Wl_g + mean_s@Wl_s + x@(WrA+WrB) + blG+blS)
// ---------------------------------------------------------------------------
__global__ __launch_bounds__(256, 2) void gemm_pf3_kernel(
    int n, const float* __restrict__ x,
    const float* __restrict__ WrA, const float* __restrict__ WrB,
    const float* __restrict__ mean_g, const float* __restrict__ Wl_g,
    const float* __restrict__ mean_s, const float* __restrict__ Wl_s,
    const float* __restrict__ blG, const float* __restrict__ blS,
    float* __restrict__ out)
{
    __shared__ float sW[32 * 128];
    __shared__ float sX[32 * 128];
    const int tid = threadIdx.x;
    const int row0 = blockIdx.x * 128;
    float4 acc[16];
#pragma unroll
    for (int i = 0; i < 16; ++i) acc[i] = make_float4(0.f, 0.f, 0.f, 0.f);
    tile_gemm<256>(mean_g, Wl_g, nullptr, n, row0, tid, (float4*)sW, sX, acc);
    tile_gemm<256>(mean_s, Wl_s, nullptr, n, row0, tid, (float4*)sW, sX, acc);
    tile_gemm<256>(x, WrA, WrB, n, row0, tid, (float4*)sW, sX, acc);

    const int tx = tid & 31;
    const int rbase = row0 + (tid >> 5) * 16;
    float4 b1 = ((const float4*)blG)[tx];
    float4 b2 = ((const float4*)blS)[tx];
#pragma unroll
    for (int rr = 0; rr < 16; ++rr) {
        int r = rbase + rr;
        if (r < n) {
            float4 o = acc[rr];
            o.x = fmaxf(o.x + b1.x + b2.x, 0.f);
            o.y = fmaxf(o.y + b1.y + b2.y, 0.f);
            o.z = fmaxf(o.z + b1.z + b2.z, 0.f);
            o.w = fmaxf(o.w + b1.w + b2.w, 0.f);
            ((float4*)out)[(size_t)r * 32 + tx] = o;
        }
    }
}

// ---------------------------------------------------------------------------
// Histogram into concatenated counts array.
// ---------------------------------------------------------------------------
__global__ __launch_bounds__(256) void hist_all_kernel(
    const int* __restrict__ d_pg, const int* __restrict__ d_ps,
    const int* __restrict__ d_gp, const int* __restrict__ d_sp,
    int* __restrict__ counts)
{
    int e = blockIdx.x * 256 + threadIdx.x;
    if (e < E_PG) atomicAdd(&counts[BASE_PG + d_pg[e]], 1);
    else if (e < E_PG + E_PS) atomicAdd(&counts[BASE_PS + d_ps[e - E_PG]], 1);
    else if (e < E_PG + E_PS + E_GP) atomicAdd(&counts[BASE_GP + d_gp[e - E_PG - E_PS]], 1);
    else if (e < E_TOT) atomicAdd(&counts[BASE_SP + d_sp[e - E_PG - E_PS - E_GP]], 1);
}

// ---------------------------------------------------------------------------
// 3-phase global exclusive scan over NTOT concatenated counts.
// ---------------------------------------------------------------------------
__global__ __launch_bounds__(256) void scanA_kernel(
    const int* __restrict__ counts, int* __restrict__ blockSums)
{
    __shared__ int red[256];
    int base = blockIdx.x * 2048;
    int s = 0;
#pragma unroll
    for (int i = 0; i < 8; ++i) {
        int idx = base + i * 256 + threadIdx.x;
        if (idx < NTOT) s += counts[idx];
    }
    red[threadIdx.x] = s;
    __syncthreads();
    for (int ofs = 128; ofs > 0; ofs >>= 1) {
        if (threadIdx.x < ofs) red[threadIdx.x] += red[threadIdx.x + ofs];
        __syncthreads();
    }
    if (threadIdx.x == 0) blockSums[blockIdx.x] = red[0];
}

__global__ __launch_bounds__(128) void scanB_kernel(
    int* __restrict__ blockSums, int* __restrict__ off_all)
{
    __shared__ int sp[128];
    int t = threadIdx.x;
    int v = (t < SCAN_NBLK) ? blockSums[t] : 0;
    sp[t] = v;
    __syncthreads();
    for (int ofs = 1; ofs < 128; ofs <<= 1) {
        int add = (t >= ofs) ? sp[t - ofs] : 0;
        __syncthreads();
        sp[t] += add;
        __syncthreads();
    }
    if (t < SCAN_NBLK) blockSums[t] = sp[t] - v;   // exclusive prefix
    if (t == 0) off_all[NTOT] = E_TOT;
}

// Phase C: write off_all; also seed per-bucket global cursors (gcursor).
__global__ __launch_bounds__(256) void scanC_kernel(
    const int* __restrict__ counts, const int* __restrict__ blockSums,
    int* __restrict__ off_all, int* __restrict__ gcursor)
{
    __shared__ int sp[256];
    const int t = threadIdx.x;
    const int myBase = blockIdx.x * 2048 + t * 8;
    int c[8];
    int s = 0;
#pragma unroll
    for (int i = 0; i < 8; ++i) {
        int idx = myBase + i;
        c[i] = (idx < NTOT) ? counts[idx] : 0;
        s += c[i];
    }
    sp[t] = s;
    __syncthreads();
    for (int ofs = 1; ofs < 256; ofs <<= 1) {
        int add = (t >= ofs) ? sp[t - ofs] : 0;
        __syncthreads();
        sp[t] += add;
        __syncthreads();
    }
    int run = blockSums[blockIdx.x] + sp[t] - s;
#pragma unroll
    for (int i = 0; i < 8; ++i) {
        int idx = myBase + i;
        if (idx < NTOT) {
            off_all[idx] = run;
            if ((idx & 255) == 0) gcursor[idx >> 8] = run;
        }
        run += c[i];
    }
}

// ---------------------------------------------------------------------------
// Pass 1: bin edges into 256-node buckets. Entry packed: (idx&255) | (src<<8).
// ---------------------------------------------------------------------------
__global__ __launch_bounds__(1024) void bin_kernel(
    const int* __restrict__ s_pg, const int* __restrict__ d_pg,
    const int* __restrict__ s_ps, const int* __restrict__ d_ps,
    const int* __restrict__ s_gp, const int* __restrict__ d_gp,
    const int* __restrict__ s_sp, const int* __restrict__ d_sp,
    int* __restrict__ gcursor, unsigned* __restrict__ pairs)
{
    __shared__ int hist[NB];
    __shared__ int chunkBase[NB];
    const int tid = threadIdx.x;
    for (int i = tid; i < NB; i += 1024) hist[i] = 0;
    __syncthreads();

    const int base = blockIdx.x * BIN_EPB;
    int bkt[BIN_EPT], rnk[BIN_EPT];
    unsigned pk[BIN_EPT];
#pragma unroll
    for (int k = 0; k < BIN_EPT; ++k) {
        int e = base + k * 1024 + tid;
        int idx = -1, src = 0;
        if (e < E_PG) { idx = BASE_PG + d_pg[e]; src = s_pg[e]; }
        else if (e < E_PG + E_PS) { int i2 = e - E_PG; idx = BASE_PS + d_ps[i2]; src = s_ps[i2]; }
        else if (e < E_PG + E_PS + E_GP) { int i2 = e - E_PG - E_PS; idx = BASE_GP + d_gp[i2]; src = s_gp[i2]; }
        else if (e < E_TOT) { int i2 = e - E_PG - E_PS - E_GP; idx = BASE_SP + d_sp[i2]; src = s_sp[i2]; }
        if (idx >= 0) {
            int b = idx >> 8;
            bkt[k] = b;
            rnk[k] = atomicAdd(&hist[b], 1);
            pk[k] = (unsigned)(idx & 255) | ((unsigned)src << 8);
        } else bkt[k] = -1;
    }
    __syncthreads();
    for (int i = tid; i < NB; i += 1024) {
        int c = hist[i];
        chunkBase[i] = c ? atomicAdd(&gcursor[i], c) : 0;
    }
    __syncthreads();
#pragma unroll
    for (int k = 0; k < BIN_EPT; ++k)
        if (bkt[k] >= 0) pairs[chunkBase[bkt[k]] + rnk[k]] = pk[k];
}

// ---------------------------------------------------------------------------
// Pass 2: one block per bucket; scatter into LDS segment, stream out coalesced.
// ---------------------------------------------------------------------------
__global__ __launch_bounds__(1024) void unbin_kernel(
    const unsigned* __restrict__ pairs, const int* __restrict__ off_all,
    int* __restrict__ perm_all)
{
    __shared__ int sPerm[SEG_CAP];
    __shared__ int cur[256];
    const int b = blockIdx.x;
    const int nb0 = b << 8;
    const int nb1 = min(nb0 + 256, NTOT);
    const int tid = threadIdx.x;
    const int base = off_all[nb0];
    const int end  = off_all[nb1];
    const int len = end - base;
    if (tid < nb1 - nb0) cur[tid] = off_all[nb0 + tid] - base;
    __syncthreads();

    if (len <= SEG_CAP) {
        for (int i = base + tid; i < end; i += 1024) {
            unsigned p = pairs[i];
            int pos = atomicAdd(&cur[p & 255u], 1);
            sPerm[pos] = (int)(p >> 8);
        }
        __syncthreads();
        for (int i = tid; i < len; i += 1024)
            perm_all[base + i] = sPerm[i];
    } else {
        for (int i = base + tid; i < end; i += 1024) {
            unsigned p = pairs[i];
            int pos = atomicAdd(&cur[p & 255u], 1);
            perm_all[base + pos] = (int)(p >> 8);
        }
    }
}

// ---------------------------------------------------------------------------
// Segmented mean of raw fp32 source features: one 64-lane wave per dst node.
// ---------------------------------------------------------------------------
__global__ __launch_bounds__(256) void seg_mean_kernel(
    const float2* __restrict__ x0, const int* __restrict__ off0,
    float2* __restrict__ mean0,
    const float2* __restrict__ x1, const int* __restrict__ off1,
    float2* __restrict__ mean1,
    const int* __restrict__ perm_all, int n)
{
    const float2* xsrc; const int* off; float2* mean;
    if (blockIdx.y == 0) { xsrc = x0; off = off0; mean = mean0; }
    else                 { xsrc = x1; off = off1; mean = mean1; }

    int node = blockIdx.x * 4 + (threadIdx.x >> 6);
    if (node >= n) return;
    int lane = threadIdx.x & 63;
    int lo = off[node], hi = off[node + 1];
    float2 a0 = make_float2(0.f, 0.f);
    float2 a1 = make_float2(0.f, 0.f);
    int i = lo;
    for (; i + 2 <= hi; i += 2) {
        int sa = perm_all[i];
        int sb = perm_all[i + 1];
        float2 va = xsrc[(size_t)sa * 64 + lane];
        float2 vb = xsrc[(size_t)sb * 64 + lane];
        a0.x += va.x; a0.y += va.y;
        a1.x += vb.x; a1.y += vb.y;
    }
    if (i < hi) {
        int sa = perm_all[i];
        float2 va = xsrc[(size_t)sa * 64 + lane];
        a0.x += va.x; a0.y += va.y;
    }
    float inv = 1.0f / fmaxf((float)(hi - lo), 1.0f);
    mean[(size_t)node * 64 + lane] = make_float2((a0.x + a1.x) * inv, (a0.y + a1.y) * inv);
}

// ---------------------------------------------------------------------------
// Launch
// ---------------------------------------------------------------------------
extern "C" void kernel_launch(void* const* d_in, const int* in_sizes, int n_in,
                              void* d_out, int out_size, void* d_ws, size_t ws_size,
                              hipStream_t stream)
{
    const float* x_pfas = (const float*)d_in[0];
    const float* x_gw   = (const float*)d_in[1];
    const float* x_sw   = (const float*)d_in[2];
    const int* ei_pg_src = (const int*)d_in[3];
    const int* ei_pg_dst = (const int*)d_in[4];
    const int* ei_gp_src = (const int*)d_in[5];
    const int* ei_gp_dst = (const int*)d_in[6];
    const int* ei_ps_src = (const int*)d_in[7];
    const int* ei_ps_dst = (const int*)d_in[8];
    const int* ei_sp_src = (const int*)d_in[9];
    const int* ei_sp_dst = (const int*)d_in[10];
    const float* Wl_pg = (const float*)d_in[11];
    const float* bl_pg = (const float*)d_in[12];
    const float* Wr_pg = (const float*)d_in[13];
    const float* Wl_gp = (const float*)d_in[14];
    const float* bl_gp = (const float*)d_in[15];
    const float* Wr_gp = (const float*)d_in[16];
    const float* Wl_ps = (const float*)d_in[17];
    const float* bl_ps = (const float*)d_in[18];
    const float* Wr_ps = (const float*)d_in[19];
    const float* Wl_sp = (const float*)d_in[20];
    const float* bl_sp = (const float*)d_in[21];
    const float* Wr_sp = (const float*)d_in[22];
    const float* W_gw = (const float*)d_in[23];
    const float* b_gw = (const float*)d_in[24];
    const float* W_sw = (const float*)d_in[25];
    const float* b_sw = (const float*)d_in[26];

    float* out  = (float*)d_out;
    float* h_pf = out;                         // 20000*128
    float* o_gw = out + (size_t)N_PFAS * 128;  // 100000
    float* o_sw = o_gw + N_GW;                 // 30000

    // ---- workspace layout (~56 MB) ----
    char* p = (char*)d_ws;
    auto alloc = [&](size_t bytes) { char* q = p; p += (bytes + 15) & ~(size_t)15; return q; };
    unsigned short* bufT_pg = (unsigned short*)alloc((size_t)N_PFAS * 128 * 2);
    unsigned short* bufT_ps = (unsigned short*)alloc((size_t)N_PFAS * 128 * 2);
    float* mean_gp = (float*)alloc((size_t)N_PFAS * 128 * 4);
    float* mean_sp = (float*)alloc((size_t)N_PFAS * 128 * 4);
    int* perm_all   = (int*)alloc((size_t)E_TOT * 4);
    unsigned* pairs = (unsigned*)alloc((size_t)E_TOT * 4);
    int* off_all    = (int*)alloc((size_t)(NTOT + 1) * 4);
    int* counts     = (int*)alloc((size_t)NTOT * 4);
    int* gcursor    = (int*)alloc((size_t)NB * 4);
    int* blockSums  = (int*)alloc((size_t)SCAN_NBLK * 4);

    // ---- 1. transforms of the pfas source side (bf16 out) ----
    dim3 gT((N_PFAS + 127) / 128, 2);
    gemm_t16_kernel<<<gT, 256, 0, stream>>>(
        N_PFAS, x_pfas, Wl_pg, bufT_pg, Wl_ps, bufT_ps);

    // ---- 2. CSR build: hist -> scan -> bucketed permute ----
    hipMemsetAsync(counts, 0, (size_t)NTOT * 4, stream);
    hist_all_kernel<<<(E_TOT + 255) / 256, 256, 0, stream>>>(
        ei_pg_dst, ei_ps_dst, ei_gp_dst, ei_sp_dst, counts);
    scanA_kernel<<<SCAN_NBLK, 256, 0, stream>>>(counts, blockSums);
    scanB_kernel<<<1, 128, 0, stream>>>(blockSums, off_all);
    scanC_kernel<<<SCAN_NBLK, 256, 0, stream>>>(counts, blockSums, off_all, gcursor);
    bin_kernel<<<BIN_NBLK, 1024, 0, stream>>>(
        ei_pg_src, ei_pg_dst, ei_ps_src, ei_ps_dst,
        ei_gp_src, ei_gp_dst, ei_sp_src, ei_sp_dst, gcursor, pairs);
    unbin_kernel<<<NB, 1024, 0, stream>>>(pairs, off_all, perm_all);

    // ---- 3. gw / sw fused node passes ----
    gemm_gather_scalar_kernel<<<(N_GW + 127) / 128, 512, 0, stream>>>(
        N_GW, x_gw, Wr_pg, bl_pg, bufT_pg, perm_all, off_all + BASE_PG,
        W_gw, b_gw, o_gw);
    gemm_gather_scalar_kernel<<<(N_SW + 127) / 128, 512, 0, stream>>>(
        N_SW, x_sw, Wr_ps, bl_ps, bufT_ps, perm_all, off_all + BASE_PS,
        W_sw, b_sw, o_sw);

    // ---- 4. raw segmented means into pfas ----
    dim3 gM((N_PFAS + 3) / 4, 2);
    seg_mean_kernel<<<gM, 256, 0, stream>>>(
        (const float2*)x_gw, off_all + BASE_GP, (float2*)mean_gp,
        (const float2*)x_sw, off_all + BASE_SP, (float2*)mean_sp,
        perm_all, N_PFAS);

    // ---- 5. pfas fused node pass ----
    gemm_pf3_kernel<<<(N_PFAS + 127) / 128, 256, 0, stream>>>(
        N_PFAS, x_pfas, Wr_gp, Wr_sp, mean_gp, Wl_gp, mean_sp, Wl_sp,
        bl_gp, bl_sp, h_pf);
}

// Round 8
// 685.694 us; speedup vs baseline: 1.1502x; 1.1502x over previous
//
#include <hip/hip_runtime.h>

// ---------------------------------------------------------------------------
// Problem constants
// ---------------------------------------------------------------------------
#define N_PFAS 20000
#define N_GW   100000
#define N_SW   30000
#define E_PG   1600000
#define E_GP   640000
#define E_PS   480000
#define E_SP   320000
#define E_TOT  (E_PG + E_PS + E_GP + E_SP)
// Concatenated node-count layout: [pg: N_GW][ps: N_SW][gp: N_PFAS][sp: N_PFAS]
#define BASE_PG 0
#define BASE_PS (N_GW)
#define BASE_GP (N_GW + N_SW)
#define BASE_SP (N_GW + N_SW + N_PFAS)
#define NTOT    (N_GW + N_SW + 2 * N_PFAS)
#define SCAN_NBLK ((NTOT + 2047) / 2048)
// Bucketed permute: 256 nodes per bucket.
#define NB        ((NTOT + 255) / 256)       // 665
#define BIN_EPT   12                         // edges per thread in bin pass
#define BIN_EPB   (1024 * BIN_EPT)           // 12288 edges per block
#define BIN_NBLK  ((E_TOT + BIN_EPB - 1) / BIN_EPB)
#define SEG_CAP   15360                      // LDS perm-segment capacity

// ---------------------------------------------------------------------------
// bf16 helpers (RNE pack, cheap unpack)
// ---------------------------------------------------------------------------
__device__ __forceinline__ unsigned short f2bf(float f) {
    unsigned u = __float_as_uint(f);
    u += 0x7fffu + ((u >> 16) & 1u);
    return (unsigned short)(u >> 16);
}
__device__ __forceinline__ float u2f(unsigned u) { return __uint_as_float(u); }

// ---------------------------------------------------------------------------
// Shared 128x128 GEMM tile: NT threads, 128 rows/block, 32-k chunks in LDS.
// acc is ALWAYS accessed with compile-time indices (fully unrolled) so it
// stays in VGPRs — dynamic indexing demotes it to scratch (HBM!).
// ---------------------------------------------------------------------------
template<int NT>
__device__ __forceinline__ void tile_gemm(
    const float* __restrict__ X, const float* __restrict__ Wa,
    const float* __restrict__ Wb, int n, int row0, int tid,
    float4* sW4, float* sX, float4* acc)
{
    constexpr int TY  = NT / 32;
    constexpr int RPT = 128 / TY;
    const int tx = tid & 31;
    const int ty = tid >> 5;
    const float4* X4 = (const float4*)X;
    const float4* Wa4 = (const float4*)Wa;
    const float4* Wb4 = (const float4*)Wb;

    for (int kc = 0; kc < 4; ++kc) {
        __syncthreads();
        for (int i = tid; i < 1024; i += NT) {
            float4 w = Wa4[kc * 1024 + i];
            if (Wb) {
                float4 b = Wb4[kc * 1024 + i];
                w.x += b.x; w.y += b.y; w.z += b.z; w.w += b.w;
            }
            sW4[i] = w;
        }
        for (int j = tid; j < 1024; j += NT) {
            int rr = j >> 3, k4 = j & 7;
            int r = row0 + rr;
            float4 xv = make_float4(0.f, 0.f, 0.f, 0.f);
            if (r < n) xv = X4[(size_t)r * 32 + kc * 8 + k4];
            int kk = k4 * 4;
            sX[(kk + 0) * 128 + rr] = xv.x;
            sX[(kk + 1) * 128 + rr] = xv.y;
            sX[(kk + 2) * 128 + rr] = xv.z;
            sX[(kk + 3) * 128 + rr] = xv.w;
        }
        __syncthreads();
#pragma unroll 4
        for (int k = 0; k < 32; ++k) {
            float4 w4 = sW4[k * 32 + tx];
            const float4* xr4 = (const float4*)&sX[k * 128 + ty * RPT];
#pragma unroll
            for (int q = 0; q < RPT / 4; ++q) {
                float4 x4 = xr4[q];
                acc[q * 4 + 0].x += x4.x * w4.x; acc[q * 4 + 0].y += x4.x * w4.y;
                acc[q * 4 + 0].z += x4.x * w4.z; acc[q * 4 + 0].w += x4.x * w4.w;
                acc[q * 4 + 1].x += x4.y * w4.x; acc[q * 4 + 1].y += x4.y * w4.y;
                acc[q * 4 + 1].z += x4.y * w4.z; acc[q * 4 + 1].w += x4.y * w4.w;
                acc[q * 4 + 2].x += x4.z * w4.x; acc[q * 4 + 2].y += x4.z * w4.y;
                acc[q * 4 + 2].z += x4.z * w4.z; acc[q * 4 + 2].w += x4.z * w4.w;
                acc[q * 4 + 3].x += x4.w * w4.x; acc[q * 4 + 3].y += x4.w * w4.y;
                acc[q * 4 + 3].z += x4.w * w4.z; acc[q * 4 + 3].w += x4.w * w4.w;
            }
        }
    }
}

// ---------------------------------------------------------------------------
// bufT16 = X @ W  (bf16 output). grid.y selects (W0,out0) vs (W1,out1).
// ---------------------------------------------------------------------------
__global__ __launch_bounds__(256, 2) void gemm_t16_kernel(
    int n, const float* __restrict__ X,
    const float* __restrict__ W0, unsigned short* __restrict__ out0,
    const float* __restrict__ W1, unsigned short* __restrict__ out1)
{
    __shared__ float sW[32 * 128];
    __shared__ float sX[32 * 128];
    const int tid = threadIdx.x;
    const int row0 = blockIdx.x * 128;
    const float* W = (blockIdx.y == 0) ? W0 : W1;
    unsigned short* out = (blockIdx.y == 0) ? out0 : out1;

    float4 acc[16];
#pragma unroll
    for (int i = 0; i < 16; ++i) acc[i] = make_float4(0.f, 0.f, 0.f, 0.f);
    tile_gemm<256>(X, W, nullptr, n, row0, tid, (float4*)sW, sX, acc);

    const int tx = tid & 31;
    const int rbase = row0 + (tid >> 5) * 16;
#pragma unroll
    for (int rr = 0; rr < 16; ++rr) {
        int r = rbase + rr;
        if (r < n) {
            uint2 o;
            o.x = (unsigned)f2bf(acc[rr].x) | ((unsigned)f2bf(acc[rr].y) << 16);
            o.y = (unsigned)f2bf(acc[rr].z) | ((unsigned)f2bf(acc[rr].w) << 16);
            *(uint2*)(out + (size_t)r * 128 + tx * 4) = o;
        }
    }
}

// ---------------------------------------------------------------------------
// gw/sw node pass, 512 threads: GEMM X@Wr fused with CSR gather of bf16
// transformed neighbor rows + scalar head.
// Epilogue FULLY UNROLLED so acc[rr] is compile-time indexed (VGPR-resident);
// the prior `#pragma unroll 1` version forced acc to scratch -> 250 MB HBM
// writes/dispatch. 4-way ILP in the segment walk hides L3 gather latency.
// ---------------------------------------------------------------------------
__global__ __launch_bounds__(512, 4) void gemm_gather_scalar_kernel(
    int n, const float* __restrict__ X, const float* __restrict__ Wr,
    const float* __restrict__ bl,
    const unsigned short* __restrict__ bufT16, const int* __restrict__ perm,
    const int* __restrict__ off,
    const float* __restrict__ wout, const float* __restrict__ bout,
    float* __restrict__ out)
{
    __shared__ float sW[32 * 128];
    __shared__ float sX[32 * 128];
    const int tid = threadIdx.x;
    const int row0 = blockIdx.x * 128;
    float4 acc[8];
#pragma unroll
    for (int i = 0; i < 8; ++i) acc[i] = make_float4(0.f, 0.f, 0.f, 0.f);
    tile_gemm<512>(X, Wr, nullptr, n, row0, tid, (float4*)sW, sX, acc);

    const int tx = tid & 31;
    const int rbase = row0 + (tid >> 5) * 8;
    float4 bv = ((const float4*)bl)[tx];
    float4 wo = ((const float4*)wout)[tx];
    float bo = bout[0];

#pragma unroll
    for (int rr = 0; rr < 8; ++rr) {
        int r = rbase + rr;
        int lo = 0, hi = 0;
        if (r < n) { lo = off[r]; hi = off[r + 1]; }
        float4 s0 = make_float4(0.f, 0.f, 0.f, 0.f);
        float4 s1 = make_float4(0.f, 0.f, 0.f, 0.f);
        float4 s2 = make_float4(0.f, 0.f, 0.f, 0.f);
        float4 s3 = make_float4(0.f, 0.f, 0.f, 0.f);
        int i = lo;
        for (; i + 4 <= hi; i += 4) {
            int a = perm[i];
            int b = perm[i + 1];
            int c = perm[i + 2];
            int d = perm[i + 3];
            uint2 va = *(const uint2*)(bufT16 + (size_t)a * 128 + tx * 4);
            uint2 vb = *(const uint2*)(bufT16 + (size_t)b * 128 + tx * 4);
            uint2 vc = *(const uint2*)(bufT16 + (size_t)c * 128 + tx * 4);
            uint2 vd = *(const uint2*)(bufT16 + (size_t)d * 128 + tx * 4);
            s0.x += u2f(va.x << 16); s0.y += u2f(va.x & 0xffff0000u);
            s0.z += u2f(va.y << 16); s0.w += u2f(va.y & 0xffff0000u);
            s1.x += u2f(vb.x << 16); s1.y += u2f(vb.x & 0xffff0000u);
            s1.z += u2f(vb.y << 16); s1.w += u2f(vb.y & 0xffff0000u);
            s2.x += u2f(vc.x << 16); s2.y += u2f(vc.x & 0xffff0000u);
            s2.z += u2f(vc.y << 16); s2.w += u2f(vc.y & 0xffff0000u);
            s3.x += u2f(vd.x << 16); s3.y += u2f(vd.x & 0xffff0000u);
            s3.z += u2f(vd.y << 16); s3.w += u2f(vd.y & 0xffff0000u);
        }
        for (; i < hi; ++i) {
            int a = perm[i];
            uint2 va = *(const uint2*)(bufT16 + (size_t)a * 128 + tx * 4);
            s0.x += u2f(va.x << 16); s0.y += u2f(va.x & 0xffff0000u);
            s0.z += u2f(va.y << 16); s0.w += u2f(va.y & 0xffff0000u);
        }
        float inv = 1.0f / fmaxf((float)(hi - lo), 1.0f);
        float h0 = fmaxf(acc[rr].x + bv.x + (s0.x + s1.x + s2.x + s3.x) * inv, 0.f);
        float h1 = fmaxf(acc[rr].y + bv.y + (s0.y + s1.y + s2.y + s3.y) * inv, 0.f);
        float h2 = fmaxf(acc[rr].z + bv.z + (s0.z + s1.z + s2.z + s3.z) * inv, 0.f);
        float h3 = fmaxf(acc[rr].w + bv.w + (s0.w + s1.w + s2.w + s3.w) * inv, 0.f);
        float p = h0 * wo.x + h1 * wo.y + h2 * wo.z + h3 * wo.w;
        p += __shfl_xor(p, 1, 32);
        p += __shfl_xor(p, 2, 32);
        p += __shfl_xor(p, 4, 32);
        p += __shfl_xor(p, 8, 32);
        p += __shfl_xor(p, 16, 32);
        if (tx == 0 && r < n) out[r] = p + bo;
    }
}

// ---------------------------------------------------------------------------
// pfas node pass: h_pf = relu(mean_g@Wl_g + mean_s@Wl_s + x@(WrA+WrB) + blG+blS)
// ---------------------------------------------------------------------------
__global__ __launch_bounds__(256, 2) void gemm_pf3_kernel(
    int n, const float* __restrict__ x,
    const float* __restrict__ WrA, const float* __restrict__ WrB,
    const float* __restrict__ mean_g, const float* __restrict__ Wl_g,
    const float* __restrict__ mean_s, const float* __restrict__ Wl_s,
    const float* __restrict__ blG, const float* __restrict__ blS,
    float* __restrict__ out)
{
    __shared__ float sW[32 * 128];
    __shared__ float sX[32 * 128];
    const int tid = threadIdx.x;
    const int row0 = blockIdx.x * 128;
    float4 acc[16];
#pragma unroll
    for (int i = 0; i < 16; ++i) acc[i] = make_float4(0.f, 0.f, 0.f, 0.f);
    tile_gemm<256>(mean_g, Wl_g, nullptr, n, row0, tid, (float4*)sW, sX, acc);
    tile_gemm<256>(mean_s, Wl_s, nullptr, n, row0, tid, (float4*)sW, sX, acc);
    tile_gemm<256>(x, WrA, WrB, n, row0, tid, (float4*)sW, sX, acc);

    const int tx = tid & 31;
    const int rbase = row0 + (tid >> 5) * 16;
    float4 b1 = ((const float4*)blG)[tx];
    float4 b2 = ((const float4*)blS)[tx];
#pragma unroll
    for (int rr = 0; rr < 16; ++rr) {
        int r = rbase + rr;
        if (r < n) {
            float4 o = acc[rr];
            o.x = fmaxf(o.x + b1.x + b2.x, 0.f);
            o.y = fmaxf(o.y + b1.y + b2.y, 0.f);
            o.z = fmaxf(o.z + b1.z + b2.z, 0.f);
            o.w = fmaxf(o.w + b1.w + b2.w, 0.f);
            ((float4*)out)[(size_t)r * 32 + tx] = o;
        }
    }
}

// ---------------------------------------------------------------------------
// Histogram into concatenated counts array.
// ---------------------------------------------------------------------------
__global__ __launch_bounds__(256) void hist_all_kernel(
    const int* __restrict__ d_pg, const int* __restrict__ d_ps,
    const int* __restrict__ d_gp, const int* __restrict__ d_sp,
    int* __restrict__ counts)
{
    int e = blockIdx.x * 256 + threadIdx.x;
    if (e < E_PG) atomicAdd(&counts[BASE_PG + d_pg[e]], 1);
    else if (e < E_PG + E_PS) atomicAdd(&counts[BASE_PS + d_ps[e - E_PG]], 1);
    else if (e < E_PG + E_PS + E_GP) atomicAdd(&counts[BASE_GP + d_gp[e - E_PG - E_PS]], 1);
    else if (e < E_TOT) atomicAdd(&counts[BASE_SP + d_sp[e - E_PG - E_PS - E_GP]], 1);
}

// ---------------------------------------------------------------------------
// 3-phase global exclusive scan over NTOT concatenated counts.
// ---------------------------------------------------------------------------
__global__ __launch_bounds__(256) void scanA_kernel(
    const int* __restrict__ counts, int* __restrict__ blockSums)
{
    __shared__ int red[256];
    int base = blockIdx.x * 2048;
    int s = 0;
#pragma unroll
    for (int i = 0; i < 8; ++i) {
        int idx = base + i * 256 + threadIdx.x;
        if (idx < NTOT) s += counts[idx];
    }
    red[threadIdx.x] = s;
    __syncthreads();
    for (int ofs = 128; ofs > 0; ofs >>= 1) {
        if (threadIdx.x < ofs) red[threadIdx.x] += red[threadIdx.x + ofs];
        __syncthreads();
    }
    if (threadIdx.x == 0) blockSums[blockIdx.x] = red[0];
}

__global__ __launch_bounds__(128) void scanB_kernel(
    int* __restrict__ blockSums, int* __restrict__ off_all)
{
    __shared__ int sp[128];
    int t = threadIdx.x;
    int v = (t < SCAN_NBLK) ? blockSums[t] : 0;
    sp[t] = v;
    __syncthreads();
    for (int ofs = 1; ofs < 128; ofs <<= 1) {
        int add = (t >= ofs) ? sp[t - ofs] : 0;
        __syncthreads();
        sp[t] += add;
        __syncthreads();
    }
    if (t < SCAN_NBLK) blockSums[t] = sp[t] - v;   // exclusive prefix
    if (t == 0) off_all[NTOT] = E_TOT;
}

// Phase C: write off_all; also seed per-bucket global cursors (gcursor).
__global__ __launch_bounds__(256) void scanC_kernel(
    const int* __restrict__ counts, const int* __restrict__ blockSums,
    int* __restrict__ off_all, int* __restrict__ gcursor)
{
    __shared__ int sp[256];
    const int t = threadIdx.x;
    const int myBase = blockIdx.x * 2048 + t * 8;
    int c[8];
    int s = 0;
#pragma unroll
    for (int i = 0; i < 8; ++i) {
        int idx = myBase + i;
        c[i] = (idx < NTOT) ? counts[idx] : 0;
        s += c[i];
    }
    sp[t] = s;
    __syncthreads();
    for (int ofs = 1; ofs < 256; ofs <<= 1) {
        int add = (t >= ofs) ? sp[t - ofs] : 0;
        __syncthreads();
        sp[t] += add;
        __syncthreads();
    }
    int run = blockSums[blockIdx.x] + sp[t] - s;
#pragma unroll
    for (int i = 0; i < 8; ++i) {
        int idx = myBase + i;
        if (idx < NTOT) {
            off_all[idx] = run;
            if ((idx & 255) == 0) gcursor[idx >> 8] = run;
        }
        run += c[i];
    }
}

// ---------------------------------------------------------------------------
// Pass 1: bin edges into 256-node buckets. Entry packed: (idx&255) | (src<<8).
// ---------------------------------------------------------------------------
__global__ __launch_bounds__(1024) void bin_kernel(
    const int* __restrict__ s_pg, const int* __restrict__ d_pg,
    const int* __restrict__ s_ps, const int* __restrict__ d_ps,
    const int* __restrict__ s_gp, const int* __restrict__ d_gp,
    const int* __restrict__ s_sp, const int* __restrict__ d_sp,
    int* __restrict__ gcursor, unsigned* __restrict__ pairs)
{
    __shared__ int hist[NB];
    __shared__ int chunkBase[NB];
    const int tid = threadIdx.x;
    for (int i = tid; i < NB; i += 1024) hist[i] = 0;
    __syncthreads();

    const int base = blockIdx.x * BIN_EPB;
    int bkt[BIN_EPT], rnk[BIN_EPT];
    unsigned pk[BIN_EPT];
#pragma unroll
    for (int k = 0; k < BIN_EPT; ++k) {
        int e = base + k * 1024 + tid;
        int idx = -1, src = 0;
        if (e < E_PG) { idx = BASE_PG + d_pg[e]; src = s_pg[e]; }
        else if (e < E_PG + E_PS) { int i2 = e - E_PG; idx = BASE_PS + d_ps[i2]; src = s_ps[i2]; }
        else if (e < E_PG + E_PS + E_GP) { int i2 = e - E_PG - E_PS; idx = BASE_GP + d_gp[i2]; src = s_gp[i2]; }
        else if (e < E_TOT) { int i2 = e - E_PG - E_PS - E_GP; idx = BASE_SP + d_sp[i2]; src = s_sp[i2]; }
        if (idx >= 0) {
            int b = idx >> 8;
            bkt[k] = b;
            rnk[k] = atomicAdd(&hist[b], 1);
            pk[k] = (unsigned)(idx & 255) | ((unsigned)src << 8);
        } else bkt[k] = -1;
    }
    __syncthreads();
    for (int i = tid; i < NB; i += 1024) {
        int c = hist[i];
        chunkBase[i] = c ? atomicAdd(&gcursor[i], c) : 0;
    }
    __syncthreads();
#pragma unroll
    for (int k = 0; k < BIN_EPT; ++k)
        if (bkt[k] >= 0) pairs[chunkBase[bkt[k]] + rnk[k]] = pk[k];
}

// ---------------------------------------------------------------------------
// Pass 2: one block per bucket; scatter into LDS segment, stream out coalesced.
// ---------------------------------------------------------------------------
__global__ __launch_bounds__(1024) void unbin_kernel(
    const unsigned* __restrict__ pairs, const int* __restrict__ off_all,
    int* __restrict__ perm_all)
{
    __shared__ int sPerm[SEG_CAP];
    __shared__ int cur[256];
    const int b = blockIdx.x;
    const int nb0 = b << 8;
    const int nb1 = min(nb0 + 256, NTOT);
    const int tid = threadIdx.x;
    const int base = off_all[nb0];
    const int end  = off_all[nb1];
    const int len = end - base;
    if (tid < nb1 - nb0) cur[tid] = off_all[nb0 + tid] - base;
    __syncthreads();

    if (len <= SEG_CAP) {
        for (int i = base + tid; i < end; i += 1024) {
            unsigned p = pairs[i];
            int pos = atomicAdd(&cur[p & 255u], 1);
            sPerm[pos] = (int)(p >> 8);
        }
        __syncthreads();
        for (int i = tid; i < len; i += 1024)
            perm_all[base + i] = sPerm[i];
    } else {
        for (int i = base + tid; i < end; i += 1024) {
            unsigned p = pairs[i];
            int pos = atomicAdd(&cur[p & 255u], 1);
            perm_all[base + pos] = (int)(p >> 8);
        }
    }
}

// ---------------------------------------------------------------------------
// Segmented mean of raw fp32 source features: one 64-lane wave per dst node.
// ---------------------------------------------------------------------------
__global__ __launch_bounds__(256) void seg_mean_kernel(
    const float2* __restrict__ x0, const int* __restrict__ off0,
    float2* __restrict__ mean0,
    const float2* __restrict__ x1, const int* __restrict__ off1,
    float2* __restrict__ mean1,
    const int* __restrict__ perm_all, int n)
{
    const float2* xsrc; const int* off; float2* mean;
    if (blockIdx.y == 0) { xsrc = x0; off = off0; mean = mean0; }
    else                 { xsrc = x1; off = off1; mean = mean1; }

    int node = blockIdx.x * 4 + (threadIdx.x >> 6);
    if (node >= n) return;
    int lane = threadIdx.x & 63;
    int lo = off[node], hi = off[node + 1];
    float2 a0 = make_float2(0.f, 0.f);
    float2 a1 = make_float2(0.f, 0.f);
    int i = lo;
    for (; i + 2 <= hi; i += 2) {
        int sa = perm_all[i];
        int sb = perm_all[i + 1];
        float2 va = xsrc[(size_t)sa * 64 + lane];
        float2 vb = xsrc[(size_t)sb * 64 + lane];
        a0.x += va.x; a0.y += va.y;
        a1.x += vb.x; a1.y += vb.y;
    }
    if (i < hi) {
        int sa = perm_all[i];
        float2 va = xsrc[(size_t)sa * 64 + lane];
        a0.x += va.x; a0.y += va.y;
    }
    float inv = 1.0f / fmaxf((float)(hi - lo), 1.0f);
    mean[(size_t)node * 64 + lane] = make_float2((a0.x + a1.x) * inv, (a0.y + a1.y) * inv);
}

// ---------------------------------------------------------------------------
// Launch
// ---------------------------------------------------------------------------
extern "C" void kernel_launch(void* const* d_in, const int* in_sizes, int n_in,
                              void* d_out, int out_size, void* d_ws, size_t ws_size,
                              hipStream_t stream)
{
    const float* x_pfas = (const float*)d_in[0];
    const float* x_gw   = (const float*)d_in[1];
    const float* x_sw   = (const float*)d_in[2];
    const int* ei_pg_src = (const int*)d_in[3];
    const int* ei_pg_dst = (const int*)d_in[4];
    const int* ei_gp_src = (const int*)d_in[5];
    const int* ei_gp_dst = (const int*)d_in[6];
    const int* ei_ps_src = (const int*)d_in[7];
    const int* ei_ps_dst = (const int*)d_in[8];
    const int* ei_sp_src = (const int*)d_in[9];
    const int* ei_sp_dst = (const int*)d_in[10];
    const float* Wl_pg = (const float*)d_in[11];
    const float* bl_pg = (const float*)d_in[12];
    const float* Wr_pg = (const float*)d_in[13];
    const float* Wl_gp = (const float*)d_in[14];
    const float* bl_gp = (const float*)d_in[15];
    const float* Wr_gp = (const float*)d_in[16];
    const float* Wl_ps = (const float*)d_in[17];
    const float* bl_ps = (const float*)d_in[18];
    const float* Wr_ps = (const float*)d_in[19];
    const float* Wl_sp = (const float*)d_in[20];
    const float* bl_sp = (const float*)d_in[21];
    const float* Wr_sp = (const float*)d_in[22];
    const float* W_gw = (const float*)d_in[23];
    const float* b_gw = (const float*)d_in[24];
    const float* W_sw = (const float*)d_in[25];
    const float* b_sw = (const float*)d_in[26];

    float* out  = (float*)d_out;
    float* h_pf = out;                         // 20000*128
    float* o_gw = out + (size_t)N_PFAS * 128;  // 100000
    float* o_sw = o_gw + N_GW;                 // 30000

    // ---- workspace layout (~56 MB) ----
    char* p = (char*)d_ws;
    auto alloc = [&](size_t bytes) { char* q = p; p += (bytes + 15) & ~(size_t)15; return q; };
    unsigned short* bufT_pg = (unsigned short*)alloc((size_t)N_PFAS * 128 * 2);
    unsigned short* bufT_ps = (unsigned short*)alloc((size_t)N_PFAS * 128 * 2);
    float* mean_gp = (float*)alloc((size_t)N_PFAS * 128 * 4);
    float* mean_sp = (float*)alloc((size_t)N_PFAS * 128 * 4);
    int* perm_all   = (int*)alloc((size_t)E_TOT * 4);
    unsigned* pairs = (unsigned*)alloc((size_t)E_TOT * 4);
    int* off_all    = (int*)alloc((size_t)(NTOT + 1) * 4);
    int* counts     = (int*)alloc((size_t)NTOT * 4);
    int* gcursor    = (int*)alloc((size_t)NB * 4);
    int* blockSums  = (int*)alloc((size_t)SCAN_NBLK * 4);

    // ---- 1. transforms of the pfas source side (bf16 out) ----
    dim3 gT((N_PFAS + 127) / 128, 2);
    gemm_t16_kernel<<<gT, 256, 0, stream>>>(
        N_PFAS, x_pfas, Wl_pg, bufT_pg, Wl_ps, bufT_ps);

    // ---- 2. CSR build: hist -> scan -> bucketed permute ----
    hipMemsetAsync(counts, 0, (size_t)NTOT * 4, stream);
    hist_all_kernel<<<(E_TOT + 255) / 256, 256, 0, stream>>>(
        ei_pg_dst, ei_ps_dst, ei_gp_dst, ei_sp_dst, counts);
    scanA_kernel<<<SCAN_NBLK, 256, 0, stream>>>(counts, blockSums);
    scanB_kernel<<<1, 128, 0, stream>>>(blockSums, off_all);
    scanC_kernel<<<SCAN_NBLK, 256, 0, stream>>>(counts, blockSums, off_all, gcursor);
    bin_kernel<<<BIN_NBLK, 1024, 0, stream>>>(
        ei_pg_src, ei_pg_dst, ei_ps_src, ei_ps_dst,
        ei_gp_src, ei_gp_dst, ei_sp_src, ei_sp_dst, gcursor, pairs);
    unbin_kernel<<<NB, 1024, 0, stream>>>(pairs, off_all, perm_all);

    // ---- 3. gw / sw fused node passes ----
    gemm_gather_scalar_kernel<<<(N_GW + 127) / 128, 512, 0, stream>>>(
        N_GW, x_gw, Wr_pg, bl_pg, bufT_pg, perm_all, off_all + BASE_PG,
        W_gw, b_gw, o_gw);
    gemm_gather_scalar_kernel<<<(N_SW + 127) / 128, 512, 0, stream>>>(
        N_SW, x_sw, Wr_ps, bl_ps, bufT_ps, perm_all, off_all + BASE_PS,
        W_sw, b_sw, o_sw);

    // ---- 4. raw segmented means into pfas ----
    dim3 gM((N_PFAS + 3) / 4, 2);
    seg_mean_kernel<<<gM, 256, 0, stream>>>(
        (const float2*)x_gw, off_all + BASE_GP, (float2*)mean_gp,
        (const float2*)x_sw, off_all + BASE_SP, (float2*)mean_sp,
        perm_all, N_PFAS);

    // ---- 5. pfas fused node pass ----
    gemm_pf3_kernel<<<(N_PFAS + 127) / 128, 256, 0, stream>>>(
        N_PFAS, x_pfas, Wr_gp, Wr_sp, mean_gp, Wl_gp, mean_sp, Wl_sp,
        bl_gp, bl_sp, h_pf);
}

// Round 9
// 630.728 us; speedup vs baseline: 1.2504x; 1.0871x over previous
//
#include <hip/hip_runtime.h>

// ---------------------------------------------------------------------------
// Problem constants
// ---------------------------------------------------------------------------
#define N_PFAS 20000
#define N_GW   100000
#define N_SW   30000
#define E_PG   1600000
#define E_GP   640000
#define E_PS   480000
#define E_SP   320000
#define E_TOT  (E_PG + E_PS + E_GP + E_SP)
// Concatenated node-count layout: [pg: N_GW][ps: N_SW][gp: N_PFAS][sp: N_PFAS]
#define BASE_PG 0
#define BASE_PS (N_GW)
#define BASE_GP (N_GW + N_SW)
#define BASE_SP (N_GW + N_SW + N_PFAS)
#define NTOT    (N_GW + N_SW + 2 * N_PFAS)
#define SCAN_NBLK ((NTOT + 2047) / 2048)
// Bucketed permute: 256 nodes per bucket.
#define NB        ((NTOT + 255) / 256)       // 665
#define BIN_EPT   12
#define BIN_EPB   (1024 * BIN_EPT)
#define BIN_NBLK  ((E_TOT + BIN_EPB - 1) / BIN_EPB)
#define SEG_CAP   15360
// Unified transform pass tiles (128 rows each)
#define TILES_PF  ((N_PFAS + 127) / 128)     // 157
#define TILES_GW  ((N_GW + 127) / 128)       // 782
#define TILES_SW  ((N_SW + 127) / 128)       // 235
#define TILES_ALL (2 * TILES_PF + TILES_GW + TILES_SW)

// ---------------------------------------------------------------------------
// bf16 helpers
// ---------------------------------------------------------------------------
__device__ __forceinline__ unsigned short f2bf(float f) {
    unsigned u = __float_as_uint(f);
    u += 0x7fffu + ((u >> 16) & 1u);
    return (unsigned short)(u >> 16);
}
__device__ __forceinline__ float u2f(unsigned u) { return __uint_as_float(u); }

// ---------------------------------------------------------------------------
// GEMM tile: NT threads, ROWS rows/block, 32-k chunks in LDS.
// acc must be compile-time indexed by callers (dynamic indexing -> scratch!).
// ---------------------------------------------------------------------------
template<int NT, int ROWS>
__device__ __forceinline__ void tile_gemm(
    const float* __restrict__ X, const float* __restrict__ Wa,
    const float* __restrict__ Wb, int n, int row0, int tid,
    float4* sW4, float* sX, float4* acc)
{
    constexpr int TY  = NT / 32;
    constexpr int RPT = ROWS / TY;
    const int tx = tid & 31;
    const int ty = tid >> 5;
    const float4* X4 = (const float4*)X;
    const float4* Wa4 = (const float4*)Wa;
    const float4* Wb4 = (const float4*)Wb;

    for (int kc = 0; kc < 4; ++kc) {
        __syncthreads();
        for (int i = tid; i < 1024; i += NT) {
            float4 w = Wa4[kc * 1024 + i];
            if (Wb) {
                float4 b = Wb4[kc * 1024 + i];
                w.x += b.x; w.y += b.y; w.z += b.z; w.w += b.w;
            }
            sW4[i] = w;
        }
        for (int j = tid; j < ROWS * 8; j += NT) {
            int rr = j >> 3, k4 = j & 7;
            int r = row0 + rr;
            float4 xv = make_float4(0.f, 0.f, 0.f, 0.f);
            if (r < n) xv = X4[(size_t)r * 32 + kc * 8 + k4];
            int kk = k4 * 4;
            sX[(kk + 0) * ROWS + rr] = xv.x;
            sX[(kk + 1) * ROWS + rr] = xv.y;
            sX[(kk + 2) * ROWS + rr] = xv.z;
            sX[(kk + 3) * ROWS + rr] = xv.w;
        }
        __syncthreads();
#pragma unroll 4
        for (int k = 0; k < 32; ++k) {
            float4 w4 = sW4[k * 32 + tx];
            const float4* xr4 = (const float4*)&sX[k * ROWS + ty * RPT];
#pragma unroll
            for (int q = 0; q < RPT / 4; ++q) {
                float4 x4 = xr4[q];
                acc[q * 4 + 0].x += x4.x * w4.x; acc[q * 4 + 0].y += x4.x * w4.y;
                acc[q * 4 + 0].z += x4.x * w4.z; acc[q * 4 + 0].w += x4.x * w4.w;
                acc[q * 4 + 1].x += x4.y * w4.x; acc[q * 4 + 1].y += x4.y * w4.y;
                acc[q * 4 + 1].z += x4.y * w4.z; acc[q * 4 + 1].w += x4.y * w4.w;
                acc[q * 4 + 2].x += x4.z * w4.x; acc[q * 4 + 2].y += x4.z * w4.y;
                acc[q * 4 + 2].z += x4.z * w4.z; acc[q * 4 + 2].w += x4.z * w4.w;
                acc[q * 4 + 3].x += x4.w * w4.x; acc[q * 4 + 3].y += x4.w * w4.y;
                acc[q * 4 + 3].z += x4.w * w4.z; acc[q * 4 + 3].w += x4.w * w4.w;
            }
        }
    }
}

// ---------------------------------------------------------------------------
// Unified transform pass: bufT_* = X @ Wl  (bf16 out) for all 4 relations.
// 1331 blocks of 128 rows.
// ---------------------------------------------------------------------------
__global__ __launch_bounds__(256, 2) void gemm_t16_all_kernel(
    const float* __restrict__ x_pfas, const float* __restrict__ x_gw,
    const float* __restrict__ x_sw,
    const float* __restrict__ Wl_pg, const float* __restrict__ Wl_ps,
    const float* __restrict__ Wl_gp, const float* __restrict__ Wl_sp,
    unsigned short* __restrict__ bufT_pg, unsigned short* __restrict__ bufT_ps,
    unsigned short* __restrict__ bufT_gp, unsigned short* __restrict__ bufT_sp)
{
    __shared__ float sW[32 * 128];
    __shared__ float sX[32 * 128];
    const int b = blockIdx.x;
    const float* X; const float* W; unsigned short* out; int n; int tile;
    if (b < TILES_PF)            { X = x_pfas; W = Wl_pg; out = bufT_pg; n = N_PFAS; tile = b; }
    else if (b < 2 * TILES_PF)   { X = x_pfas; W = Wl_ps; out = bufT_ps; n = N_PFAS; tile = b - TILES_PF; }
    else if (b < 2 * TILES_PF + TILES_GW)
                                 { X = x_gw;   W = Wl_gp; out = bufT_gp; n = N_GW;   tile = b - 2 * TILES_PF; }
    else                         { X = x_sw;   W = Wl_sp; out = bufT_sp; n = N_SW;   tile = b - 2 * TILES_PF - TILES_GW; }
    const int tid = threadIdx.x;
    const int row0 = tile * 128;

    float4 acc[16];
#pragma unroll
    for (int i = 0; i < 16; ++i) acc[i] = make_float4(0.f, 0.f, 0.f, 0.f);
    tile_gemm<256, 128>(X, W, nullptr, n, row0, tid, (float4*)sW, sX, acc);

    const int tx = tid & 31;
    const int rbase = row0 + (tid >> 5) * 16;
#pragma unroll
    for (int rr = 0; rr < 16; ++rr) {
        int r = rbase + rr;
        if (r < n) {
            uint2 o;
            o.x = (unsigned)f2bf(acc[rr].x) | ((unsigned)f2bf(acc[rr].y) << 16);
            o.y = (unsigned)f2bf(acc[rr].z) | ((unsigned)f2bf(acc[rr].w) << 16);
            *(uint2*)(out + (size_t)r * 128 + tx * 4) = o;
        }
    }
}

// ---------------------------------------------------------------------------
// gw/sw node pass: 256 threads, 64 rows/block. GEMM X@Wr fused with 8-ILP
// CSR gather of bf16 transformed neighbor rows + scalar head.
// ---------------------------------------------------------------------------
__global__ __launch_bounds__(256, 4) void gemm_gather_scalar_kernel(
    int n, const float* __restrict__ X, const float* __restrict__ Wr,
    const float* __restrict__ bl,
    const unsigned short* __restrict__ bufT16, const int* __restrict__ perm,
    const int* __restrict__ off,
    const float* __restrict__ wout, const float* __restrict__ bout,
    float* __restrict__ out)
{
    __shared__ float sW[32 * 128];
    __shared__ float sX[32 * 64];
    const int tid = threadIdx.x;
    const int row0 = blockIdx.x * 64;
    float4 acc[8];
#pragma unroll
    for (int i = 0; i < 8; ++i) acc[i] = make_float4(0.f, 0.f, 0.f, 0.f);
    tile_gemm<256, 64>(X, Wr, nullptr, n, row0, tid, (float4*)sW, sX, acc);

    const int tx = tid & 31;
    const int rbase = row0 + (tid >> 5) * 8;
    float4 bv = ((const float4*)bl)[tx];
    float4 wo = ((const float4*)wout)[tx];
    float bo = bout[0];

#pragma unroll
    for (int rr = 0; rr < 8; ++rr) {
        int r = rbase + rr;
        int lo = 0, hi = 0;
        if (r < n) { lo = off[r]; hi = off[r + 1]; }
        float4 s0 = make_float4(0.f, 0.f, 0.f, 0.f);
        float4 s1 = make_float4(0.f, 0.f, 0.f, 0.f);
        float4 s2 = make_float4(0.f, 0.f, 0.f, 0.f);
        float4 s3 = make_float4(0.f, 0.f, 0.f, 0.f);
        int i = lo;
        for (; i + 8 <= hi; i += 8) {
            uint2 v0 = *(const uint2*)(bufT16 + (size_t)perm[i + 0] * 128 + tx * 4);
            uint2 v1 = *(const uint2*)(bufT16 + (size_t)perm[i + 1] * 128 + tx * 4);
            uint2 v2 = *(const uint2*)(bufT16 + (size_t)perm[i + 2] * 128 + tx * 4);
            uint2 v3 = *(const uint2*)(bufT16 + (size_t)perm[i + 3] * 128 + tx * 4);
            uint2 v4 = *(const uint2*)(bufT16 + (size_t)perm[i + 4] * 128 + tx * 4);
            uint2 v5 = *(const uint2*)(bufT16 + (size_t)perm[i + 5] * 128 + tx * 4);
            uint2 v6 = *(const uint2*)(bufT16 + (size_t)perm[i + 6] * 128 + tx * 4);
            uint2 v7 = *(const uint2*)(bufT16 + (size_t)perm[i + 7] * 128 + tx * 4);
            s0.x += u2f(v0.x << 16); s0.y += u2f(v0.x & 0xffff0000u);
            s0.z += u2f(v0.y << 16); s0.w += u2f(v0.y & 0xffff0000u);
            s1.x += u2f(v1.x << 16); s1.y += u2f(v1.x & 0xffff0000u);
            s1.z += u2f(v1.y << 16); s1.w += u2f(v1.y & 0xffff0000u);
            s2.x += u2f(v2.x << 16); s2.y += u2f(v2.x & 0xffff0000u);
            s2.z += u2f(v2.y << 16); s2.w += u2f(v2.y & 0xffff0000u);
            s3.x += u2f(v3.x << 16); s3.y += u2f(v3.x & 0xffff0000u);
            s3.z += u2f(v3.y << 16); s3.w += u2f(v3.y & 0xffff0000u);
            s0.x += u2f(v4.x << 16); s0.y += u2f(v4.x & 0xffff0000u);
            s0.z += u2f(v4.y << 16); s0.w += u2f(v4.y & 0xffff0000u);
            s1.x += u2f(v5.x << 16); s1.y += u2f(v5.x & 0xffff0000u);
            s1.z += u2f(v5.y << 16); s1.w += u2f(v5.y & 0xffff0000u);
            s2.x += u2f(v6.x << 16); s2.y += u2f(v6.x & 0xffff0000u);
            s2.z += u2f(v6.y << 16); s2.w += u2f(v6.y & 0xffff0000u);
            s3.x += u2f(v7.x << 16); s3.y += u2f(v7.x & 0xffff0000u);
            s3.z += u2f(v7.y << 16); s3.w += u2f(v7.y & 0xffff0000u);
        }
        for (; i + 2 <= hi; i += 2) {
            uint2 v0 = *(const uint2*)(bufT16 + (size_t)perm[i + 0] * 128 + tx * 4);
            uint2 v1 = *(const uint2*)(bufT16 + (size_t)perm[i + 1] * 128 + tx * 4);
            s0.x += u2f(v0.x << 16); s0.y += u2f(v0.x & 0xffff0000u);
            s0.z += u2f(v0.y << 16); s0.w += u2f(v0.y & 0xffff0000u);
            s1.x += u2f(v1.x << 16); s1.y += u2f(v1.x & 0xffff0000u);
            s1.z += u2f(v1.y << 16); s1.w += u2f(v1.y & 0xffff0000u);
        }
        if (i < hi) {
            uint2 v0 = *(const uint2*)(bufT16 + (size_t)perm[i] * 128 + tx * 4);
            s0.x += u2f(v0.x << 16); s0.y += u2f(v0.x & 0xffff0000u);
            s0.z += u2f(v0.y << 16); s0.w += u2f(v0.y & 0xffff0000u);
        }
        float inv = 1.0f / fmaxf((float)(hi - lo), 1.0f);
        float h0 = fmaxf(acc[rr].x + bv.x + (s0.x + s1.x + s2.x + s3.x) * inv, 0.f);
        float h1 = fmaxf(acc[rr].y + bv.y + (s0.y + s1.y + s2.y + s3.y) * inv, 0.f);
        float h2 = fmaxf(acc[rr].z + bv.z + (s0.z + s1.z + s2.z + s3.z) * inv, 0.f);
        float h3 = fmaxf(acc[rr].w + bv.w + (s0.w + s1.w + s2.w + s3.w) * inv, 0.f);
        float p = h0 * wo.x + h1 * wo.y + h2 * wo.z + h3 * wo.w;
        p += __shfl_xor(p, 1, 32);
        p += __shfl_xor(p, 2, 32);
        p += __shfl_xor(p, 4, 32);
        p += __shfl_xor(p, 8, 32);
        p += __shfl_xor(p, 16, 32);
        if (tx == 0 && r < n) out[r] = p + bo;
    }
}

// ---------------------------------------------------------------------------
// Segment contributions for pfas: contrib[node] = (Σ bufT16[src]) / cnt.
// Half-wave per node, 8 nodes/block, 8-ILP bf16 gather. grid.y = relation.
// ---------------------------------------------------------------------------
__global__ __launch_bounds__(256, 4) void seg_contrib_kernel(
    const unsigned short* __restrict__ bufT_gp,
    const unsigned short* __restrict__ bufT_sp,
    const int* __restrict__ off_all, const int* __restrict__ perm_all,
    float* __restrict__ contrib_gp, float* __restrict__ contrib_sp)
{
    const unsigned short* bufT; const int* off; float* contrib;
    if (blockIdx.y == 0) { bufT = bufT_gp; off = off_all + BASE_GP; contrib = contrib_gp; }
    else                 { bufT = bufT_sp; off = off_all + BASE_SP; contrib = contrib_sp; }

    int node = blockIdx.x * 8 + (threadIdx.x >> 5);
    if (node >= N_PFAS) return;
    int tx = threadIdx.x & 31;
    int lo = off[node], hi = off[node + 1];
    float4 s0 = make_float4(0.f, 0.f, 0.f, 0.f);
    float4 s1 = make_float4(0.f, 0.f, 0.f, 0.f);
    float4 s2 = make_float4(0.f, 0.f, 0.f, 0.f);
    float4 s3 = make_float4(0.f, 0.f, 0.f, 0.f);
    int i = lo;
    for (; i + 8 <= hi; i += 8) {
        uint2 v0 = *(const uint2*)(bufT + (size_t)perm_all[i + 0] * 128 + tx * 4);
        uint2 v1 = *(const uint2*)(bufT + (size_t)perm_all[i + 1] * 128 + tx * 4);
        uint2 v2 = *(const uint2*)(bufT + (size_t)perm_all[i + 2] * 128 + tx * 4);
        uint2 v3 = *(const uint2*)(bufT + (size_t)perm_all[i + 3] * 128 + tx * 4);
        uint2 v4 = *(const uint2*)(bufT + (size_t)perm_all[i + 4] * 128 + tx * 4);
        uint2 v5 = *(const uint2*)(bufT + (size_t)perm_all[i + 5] * 128 + tx * 4);
        uint2 v6 = *(const uint2*)(bufT + (size_t)perm_all[i + 6] * 128 + tx * 4);
        uint2 v7 = *(const uint2*)(bufT + (size_t)perm_all[i + 7] * 128 + tx * 4);
        s0.x += u2f(v0.x << 16); s0.y += u2f(v0.x & 0xffff0000u);
        s0.z += u2f(v0.y << 16); s0.w += u2f(v0.y & 0xffff0000u);
        s1.x += u2f(v1.x << 16); s1.y += u2f(v1.x & 0xffff0000u);
        s1.z += u2f(v1.y << 16); s1.w += u2f(v1.y & 0xffff0000u);
        s2.x += u2f(v2.x << 16); s2.y += u2f(v2.x & 0xffff0000u);
        s2.z += u2f(v2.y << 16); s2.w += u2f(v2.y & 0xffff0000u);
        s3.x += u2f(v3.x << 16); s3.y += u2f(v3.x & 0xffff0000u);
        s3.z += u2f(v3.y << 16); s3.w += u2f(v3.y & 0xffff0000u);
        s0.x += u2f(v4.x << 16); s0.y += u2f(v4.x & 0xffff0000u);
        s0.z += u2f(v4.y << 16); s0.w += u2f(v4.y & 0xffff0000u);
        s1.x += u2f(v5.x << 16); s1.y += u2f(v5.x & 0xffff0000u);
        s1.z += u2f(v5.y << 16); s1.w += u2f(v5.y & 0xffff0000u);
        s2.x += u2f(v6.x << 16); s2.y += u2f(v6.x & 0xffff0000u);
        s2.z += u2f(v6.y << 16); s2.w += u2f(v6.y & 0xffff0000u);
        s3.x += u2f(v7.x << 16); s3.y += u2f(v7.x & 0xffff0000u);
        s3.z += u2f(v7.y << 16); s3.w += u2f(v7.y & 0xffff0000u);
    }
    for (; i + 2 <= hi; i += 2) {
        uint2 v0 = *(const uint2*)(bufT + (size_t)perm_all[i + 0] * 128 + tx * 4);
        uint2 v1 = *(const uint2*)(bufT + (size_t)perm_all[i + 1] * 128 + tx * 4);
        s0.x += u2f(v0.x << 16); s0.y += u2f(v0.x & 0xffff0000u);
        s0.z += u2f(v0.y << 16); s0.w += u2f(v0.y & 0xffff0000u);
        s1.x += u2f(v1.x << 16); s1.y += u2f(v1.x & 0xffff0000u);
        s1.z += u2f(v1.y << 16); s1.w += u2f(v1.y & 0xffff0000u);
    }
    if (i < hi) {
        uint2 v0 = *(const uint2*)(bufT + (size_t)perm_all[i] * 128 + tx * 4);
        s0.x += u2f(v0.x << 16); s0.y += u2f(v0.x & 0xffff0000u);
        s0.z += u2f(v0.y << 16); s0.w += u2f(v0.y & 0xffff0000u);
    }
    float inv = 1.0f / fmaxf((float)(hi - lo), 1.0f);
    float4 o;
    o.x = (s0.x + s1.x + s2.x + s3.x) * inv;
    o.y = (s0.y + s1.y + s2.y + s3.y) * inv;
    o.z = (s0.z + s1.z + s2.z + s3.z) * inv;
    o.w = (s0.w + s1.w + s2.w + s3.w) * inv;
    ((float4*)contrib)[(size_t)node * 32 + tx] = o;
}

// ---------------------------------------------------------------------------
// pfas node pass: h_pf = relu(x@(WrA+WrB) + contrib_gp + contrib_sp + blG+blS)
// ---------------------------------------------------------------------------
__global__ __launch_bounds__(256, 2) void gemm_pf_kernel(
    int n, const float* __restrict__ x,
    const float* __restrict__ WrA, const float* __restrict__ WrB,
    const float* __restrict__ contrib_gp, const float* __restrict__ contrib_sp,
    const float* __restrict__ blG, const float* __restrict__ blS,
    float* __restrict__ out)
{
    __shared__ float sW[32 * 128];
    __shared__ float sX[32 * 128];
    const int tid = threadIdx.x;
    const int row0 = blockIdx.x * 128;
    float4 acc[16];
#pragma unroll
    for (int i = 0; i < 16; ++i) acc[i] = make_float4(0.f, 0.f, 0.f, 0.f);
    tile_gemm<256, 128>(x, WrA, WrB, n, row0, tid, (float4*)sW, sX, acc);

    const int tx = tid & 31;
    const int rbase = row0 + (tid >> 5) * 16;
    float4 b1 = ((const float4*)blG)[tx];
    float4 b2 = ((const float4*)blS)[tx];
#pragma unroll
    for (int rr = 0; rr < 16; ++rr) {
        int r = rbase + rr;
        if (r < n) {
            float4 cg = ((const float4*)contrib_gp)[(size_t)r * 32 + tx];
            float4 cs = ((const float4*)contrib_sp)[(size_t)r * 32 + tx];
            float4 o = acc[rr];
            o.x = fmaxf(o.x + cg.x + cs.x + b1.x + b2.x, 0.f);
            o.y = fmaxf(o.y + cg.y + cs.y + b1.y + b2.y, 0.f);
            o.z = fmaxf(o.z + cg.z + cs.z + b1.z + b2.z, 0.f);
            o.w = fmaxf(o.w + cg.w + cs.w + b1.w + b2.w, 0.f);
            ((float4*)out)[(size_t)r * 32 + tx] = o;
        }
    }
}

// ---------------------------------------------------------------------------
// Histogram into concatenated counts array.
// ---------------------------------------------------------------------------
__global__ __launch_bounds__(256) void hist_all_kernel(
    const int* __restrict__ d_pg, const int* __restrict__ d_ps,
    const int* __restrict__ d_gp, const int* __restrict__ d_sp,
    int* __restrict__ counts)
{
    int e = blockIdx.x * 256 + threadIdx.x;
    if (e < E_PG) atomicAdd(&counts[BASE_PG + d_pg[e]], 1);
    else if (e < E_PG + E_PS) atomicAdd(&counts[BASE_PS + d_ps[e - E_PG]], 1);
    else if (e < E_PG + E_PS + E_GP) atomicAdd(&counts[BASE_GP + d_gp[e - E_PG - E_PS]], 1);
    else if (e < E_TOT) atomicAdd(&counts[BASE_SP + d_sp[e - E_PG - E_PS - E_GP]], 1);
}

// ---------------------------------------------------------------------------
// 3-phase global exclusive scan over NTOT concatenated counts.
// ---------------------------------------------------------------------------
__global__ __launch_bounds__(256) void scanA_kernel(
    const int* __restrict__ counts, int* __restrict__ blockSums)
{
    __shared__ int red[256];
    int base = blockIdx.x * 2048;
    int s = 0;
#pragma unroll
    for (int i = 0; i < 8; ++i) {
        int idx = base + i * 256 + threadIdx.x;
        if (idx < NTOT) s += counts[idx];
    }
    red[threadIdx.x] = s;
    __syncthreads();
    for (int ofs = 128; ofs > 0; ofs >>= 1) {
        if (threadIdx.x < ofs) red[threadIdx.x] += red[threadIdx.x + ofs];
        __syncthreads();
    }
    if (threadIdx.x == 0) blockSums[blockIdx.x] = red[0];
}

__global__ __launch_bounds__(128) void scanB_kernel(
    int* __restrict__ blockSums, int* __restrict__ off_all)
{
    __shared__ int sp[128];
    int t = threadIdx.x;
    int v = (t < SCAN_NBLK) ? blockSums[t] : 0;
    sp[t] = v;
    __syncthreads();
    for (int ofs = 1; ofs < 128; ofs <<= 1) {
        int add = (t >= ofs) ? sp[t - ofs] : 0;
        __syncthreads();
        sp[t] += add;
        __syncthreads();
    }
    if (t < SCAN_NBLK) blockSums[t] = sp[t] - v;
    if (t == 0) off_all[NTOT] = E_TOT;
}

__global__ __launch_bounds__(256) void scanC_kernel(
    const int* __restrict__ counts, const int* __restrict__ blockSums,
    int* __restrict__ off_all, int* __restrict__ gcursor)
{
    __shared__ int sp[256];
    const int t = threadIdx.x;
    const int myBase = blockIdx.x * 2048 + t * 8;
    int c[8];
    int s = 0;
#pragma unroll
    for (int i = 0; i < 8; ++i) {
        int idx = myBase + i;
        c[i] = (idx < NTOT) ? counts[idx] : 0;
        s += c[i];
    }
    sp[t] = s;
    __syncthreads();
    for (int ofs = 1; ofs < 256; ofs <<= 1) {
        int add = (t >= ofs) ? sp[t - ofs] : 0;
        __syncthreads();
        sp[t] += add;
        __syncthreads();
    }
    int run = blockSums[blockIdx.x] + sp[t] - s;
#pragma unroll
    for (int i = 0; i < 8; ++i) {
        int idx = myBase + i;
        if (idx < NTOT) {
            off_all[idx] = run;
            if ((idx & 255) == 0) gcursor[idx >> 8] = run;
        }
        run += c[i];
    }
}

// ---------------------------------------------------------------------------
// Pass 1: bin edges into 256-node buckets. Entry packed: (idx&255) | (src<<8).
// ---------------------------------------------------------------------------
__global__ __launch_bounds__(1024) void bin_kernel(
    const int* __restrict__ s_pg, const int* __restrict__ d_pg,
    const int* __restrict__ s_ps, const int* __restrict__ d_ps,
    const int* __restrict__ s_gp, const int* __restrict__ d_gp,
    const int* __restrict__ s_sp, const int* __restrict__ d_sp,
    int* __restrict__ gcursor, unsigned* __restrict__ pairs)
{
    __shared__ int hist[NB];
    __shared__ int chunkBase[NB];
    const int tid = threadIdx.x;
    for (int i = tid; i < NB; i += 1024) hist[i] = 0;
    __syncthreads();

    const int base = blockIdx.x * BIN_EPB;
    int bkt[BIN_EPT], rnk[BIN_EPT];
    unsigned pk[BIN_EPT];
#pragma unroll
    for (int k = 0; k < BIN_EPT; ++k) {
        int e = base + k * 1024 + tid;
        int idx = -1, src = 0;
        if (e < E_PG) { idx = BASE_PG + d_pg[e]; src = s_pg[e]; }
        else if (e < E_PG + E_PS) { int i2 = e - E_PG; idx = BASE_PS + d_ps[i2]; src = s_ps[i2]; }
        else if (e < E_PG + E_PS + E_GP) { int i2 = e - E_PG - E_PS; idx = BASE_GP + d_gp[i2]; src = s_gp[i2]; }
        else if (e < E_TOT) { int i2 = e - E_PG - E_PS - E_GP; idx = BASE_SP + d_sp[i2]; src = s_sp[i2]; }
        if (idx >= 0) {
            int b = idx >> 8;
            bkt[k] = b;
            rnk[k] = atomicAdd(&hist[b], 1);
            pk[k] = (unsigned)(idx & 255) | ((unsigned)src << 8);
        } else bkt[k] = -1;
    }
    __syncthreads();
    for (int i = tid; i < NB; i += 1024) {
        int c = hist[i];
        chunkBase[i] = c ? atomicAdd(&gcursor[i], c) : 0;
    }
    __syncthreads();
#pragma unroll
    for (int k = 0; k < BIN_EPT; ++k)
        if (bkt[k] >= 0) pairs[chunkBase[bkt[k]] + rnk[k]] = pk[k];
}

// ---------------------------------------------------------------------------
// Pass 2: one block per bucket; scatter into LDS segment, stream out coalesced.
// ---------------------------------------------------------------------------
__global__ __launch_bounds__(1024) void unbin_kernel(
    const unsigned* __restrict__ pairs, const int* __restrict__ off_all,
    int* __restrict__ perm_all)
{
    __shared__ int sPerm[SEG_CAP];
    __shared__ int cur[256];
    const int b = blockIdx.x;
    const int nb0 = b << 8;
    const int nb1 = min(nb0 + 256, NTOT);
    const int tid = threadIdx.x;
    const int base = off_all[nb0];
    const int end  = off_all[nb1];
    const int len = end - base;
    if (tid < nb1 - nb0) cur[tid] = off_all[nb0 + tid] - base;
    __syncthreads();

    if (len <= SEG_CAP) {
        for (int i = base + tid; i < end; i += 1024) {
            unsigned p = pairs[i];
            int pos = atomicAdd(&cur[p & 255u], 1);
            sPerm[pos] = (int)(p >> 8);
        }
        __syncthreads();
        for (int i = tid; i < len; i += 1024)
            perm_all[base + i] = sPerm[i];
    } else {
        for (int i = base + tid; i < end; i += 1024) {
            unsigned p = pairs[i];
            int pos = atomicAdd(&cur[p & 255u], 1);
            perm_all[base + pos] = (int)(p >> 8);
        }
    }
}

// ---------------------------------------------------------------------------
// Launch
// ---------------------------------------------------------------------------
extern "C" void kernel_launch(void* const* d_in, const int* in_sizes, int n_in,
                              void* d_out, int out_size, void* d_ws, size_t ws_size,
                              hipStream_t stream)
{
    const float* x_pfas = (const float*)d_in[0];
    const float* x_gw   = (const float*)d_in[1];
    const float* x_sw   = (const float*)d_in[2];
    const int* ei_pg_src = (const int*)d_in[3];
    const int* ei_pg_dst = (const int*)d_in[4];
    const int* ei_gp_src = (const int*)d_in[5];
    const int* ei_gp_dst = (const int*)d_in[6];
    const int* ei_ps_src = (const int*)d_in[7];
    const int* ei_ps_dst = (const int*)d_in[8];
    const int* ei_sp_src = (const int*)d_in[9];
    const int* ei_sp_dst = (const int*)d_in[10];
    const float* Wl_pg = (const float*)d_in[11];
    const float* bl_pg = (const float*)d_in[12];
    const float* Wr_pg = (const float*)d_in[13];
    const float* Wl_gp = (const float*)d_in[14];
    const float* bl_gp = (const float*)d_in[15];
    const float* Wr_gp = (const float*)d_in[16];
    const float* Wl_ps = (const float*)d_in[17];
    const float* bl_ps = (const float*)d_in[18];
    const float* Wr_ps = (const float*)d_in[19];
    const float* Wl_sp = (const float*)d_in[20];
    const float* bl_sp = (const float*)d_in[21];
    const float* Wr_sp = (const float*)d_in[22];
    const float* W_gw = (const float*)d_in[23];
    const float* b_gw = (const float*)d_in[24];
    const float* W_sw = (const float*)d_in[25];
    const float* b_sw = (const float*)d_in[26];

    float* out  = (float*)d_out;
    float* h_pf = out;                         // 20000*128
    float* o_gw = out + (size_t)N_PFAS * 128;  // 100000
    float* o_sw = o_gw + N_GW;                 // 30000

    // ---- workspace layout (~90 MB) ----
    char* p = (char*)d_ws;
    auto alloc = [&](size_t bytes) { char* q = p; p += (bytes + 15) & ~(size_t)15; return q; };
    unsigned short* bufT_pg = (unsigned short*)alloc((size_t)N_PFAS * 128 * 2);
    unsigned short* bufT_ps = (unsigned short*)alloc((size_t)N_PFAS * 128 * 2);
    unsigned short* bufT_gp = (unsigned short*)alloc((size_t)N_GW * 128 * 2);
    unsigned short* bufT_sp = (unsigned short*)alloc((size_t)N_SW * 128 * 2);
    float* contrib_gp = (float*)alloc((size_t)N_PFAS * 128 * 4);
    float* contrib_sp = (float*)alloc((size_t)N_PFAS * 128 * 4);
    int* perm_all   = (int*)alloc((size_t)E_TOT * 4);
    unsigned* pairs = (unsigned*)alloc((size_t)E_TOT * 4);
    int* off_all    = (int*)alloc((size_t)(NTOT + 1) * 4);
    int* counts     = (int*)alloc((size_t)NTOT * 4);
    int* gcursor    = (int*)alloc((size_t)NB * 4);
    int* blockSums  = (int*)alloc((size_t)SCAN_NBLK * 4);

    // ---- 1. unified bf16 transforms (all 4 relations) ----
    gemm_t16_all_kernel<<<TILES_ALL, 256, 0, stream>>>(
        x_pfas, x_gw, x_sw, Wl_pg, Wl_ps, Wl_gp, Wl_sp,
        bufT_pg, bufT_ps, bufT_gp, bufT_sp);

    // ---- 2. CSR build: hist -> scan -> bucketed permute ----
    hipMemsetAsync(counts, 0, (size_t)NTOT * 4, stream);
    hist_all_kernel<<<(E_TOT + 255) / 256, 256, 0, stream>>>(
        ei_pg_dst, ei_ps_dst, ei_gp_dst, ei_sp_dst, counts);
    scanA_kernel<<<SCAN_NBLK, 256, 0, stream>>>(counts, blockSums);
    scanB_kernel<<<1, 128, 0, stream>>>(blockSums, off_all);
    scanC_kernel<<<SCAN_NBLK, 256, 0, stream>>>(counts, blockSums, off_all, gcursor);
    bin_kernel<<<BIN_NBLK, 1024, 0, stream>>>(
        ei_pg_src, ei_pg_dst, ei_ps_src, ei_ps_dst,
        ei_gp_src, ei_gp_dst, ei_sp_src, ei_sp_dst, gcursor, pairs);
    unbin_kernel<<<NB, 1024, 0, stream>>>(pairs, off_all, perm_all);

    // ---- 3. gw / sw fused node passes (64 rows/block) ----
    gemm_gather_scalar_kernel<<<(N_GW + 63) / 64, 256, 0, stream>>>(
        N_GW, x_gw, Wr_pg, bl_pg, bufT_pg, perm_all, off_all + BASE_PG,
        W_gw, b_gw, o_gw);
    gemm_gather_scalar_kernel<<<(N_SW + 63) / 64, 256, 0, stream>>>(
        N_SW, x_sw, Wr_ps, bl_ps, bufT_ps, perm_all, off_all + BASE_PS,
        W_sw, b_sw, o_sw);

    // ---- 4. bf16 segment contributions into pfas ----
    dim3 gS((N_PFAS + 7) / 8, 2);
    seg_contrib_kernel<<<gS, 256, 0, stream>>>(
        bufT_gp, bufT_sp, off_all, perm_all, contrib_gp, contrib_sp);

    // ---- 5. pfas node pass (single GEMM + contrib epilogue) ----
    gemm_pf_kernel<<<(N_PFAS + 127) / 128, 256, 0, stream>>>(
        N_PFAS, x_pfas, Wr_gp, Wr_sp, contrib_gp, contrib_sp,
        bl_gp, bl_sp, h_pf);
}